// Round 4
// baseline (313.486 us; speedup 1.0000x reference)
//
#include <hip/hip_runtime.h>
#include <hip/hip_bf16.h>

typedef __attribute__((ext_vector_type(8))) short short8;
typedef __attribute__((ext_vector_type(4))) short s4v;
typedef __attribute__((ext_vector_type(4))) float f32x4;

#define BATCH 4
#define TLEN 4096
#define CDIM 1024
#define HSD 128
#define MROWS (BATCH*TLEN)

// 1/sqrt(128) * log2(e): fold into Q so softmax runs in exp2 domain
#define QSCALE 0.12751744f

#ifdef __HIP_DEVICE_COMPILE__
  #define MFMA16(a,b,c) __builtin_amdgcn_mfma_f32_16x16x16bf16_1k(a,b,c,0,0,0)
#else
  #define MFMA16(a,b,c) (c)
#endif

__device__ __forceinline__ unsigned short f2bf(float f){
    unsigned u = __builtin_bit_cast(unsigned, f);
    u = (u + 0x7FFFu + ((u >> 16) & 1u)) >> 16;
    return (unsigned short)u;
}
__device__ __forceinline__ unsigned pkbf(float a, float b){
    unsigned ua = (__builtin_bit_cast(unsigned, a) + 0x8000u) >> 16;
    unsigned ub = (__builtin_bit_cast(unsigned, b) + 0x8000u) & 0xFFFF0000u;
    return ua | ub;
}

// ---------------- kernel 1: W (C,HS) fp32 -> Wt (3,HS,C) bf16, LDS transpose ----------------
__global__ void prep_w_k(const float* __restrict__ Wq, const float* __restrict__ Wk,
                         const float* __restrict__ Wv, unsigned short* __restrict__ Wt){
    __shared__ float tile[32][33];
    const int w = blockIdx.z;
    const float* W = (w == 0) ? Wq : ((w == 1) ? Wk : Wv);
    const int c0 = blockIdx.x * 32, h0 = blockIdx.y * 32;
    const int lx = threadIdx.x & 31, ly = threadIdx.x >> 5;   // ly 0..7
#pragma unroll
    for (int i = 0; i < 4; i++){
        int c = c0 + ly + i * 8;
        tile[ly + i * 8][lx] = W[(size_t)c * HSD + h0 + lx];   // coalesced read over h
    }
    __syncthreads();
#pragma unroll
    for (int i = 0; i < 4; i++){
        int h = h0 + ly + i * 8;
        Wt[((size_t)w * HSD + h) * CDIM + c0 + lx] = f2bf(tile[lx][ly + i * 8]); // coalesced write over c
    }
}

// ---------------- kernel 2: fused QKV projection GEMM (x read ONCE) ----------------
// grid (MROWS/64), block 512 (8 waves). Counted-vmcnt pipeline: issue A(next)+B(next),
// vmcnt(4) confirms prev B only, one raw barrier per K-step (no drain-0).
__device__ __forceinline__ void stage_wb(unsigned short* buf, const unsigned short* g, int tid){
#pragma unroll
    for (int i = 0; i < 3; i++){
        int c = i * 512 + tid;              // 1536 chunks: 384 rows x 4 x 16B
        int row = c >> 2, kp = c & 3;
        int swz = (row & 3) ^ ((row >> 2) & 3);
        const unsigned short* gp = g + (size_t)row * CDIM + ((kp ^ swz) << 3);
        unsigned short* lp = buf + (c << 3);
        __builtin_amdgcn_global_load_lds((const __attribute__((address_space(1))) void*)gp,
                                         (__attribute__((address_space(3))) void*)lp, 16, 0, 0);
    }
}

__global__ __launch_bounds__(512) void proj_k(const float* __restrict__ x,
                                              const unsigned short* __restrict__ Wt,
                                              unsigned short* __restrict__ Qb,
                                              unsigned short* __restrict__ Kb,
                                              unsigned short* __restrict__ Vt){
    __shared__ unsigned short As[2][64 * 32];     // 4 KB each
    __shared__ unsigned short Bs[2][384 * 32];    // 24 KB each

    const int tid = threadIdx.x, lane = tid & 63, wave = tid >> 6;
    const int m = lane & 15, quad = lane >> 4;
    const int wr = wave & 1;        // t-half (32 rows)
    const int wc = wave >> 1;       // h-quarter (96 of 384 weight rows)
    const int rb = blockIdx.x * 64;

    const float* gA = x + (size_t)rb * CDIM;

    // A staging: ALL 512 threads, 1 float4 each (uniform vmcnt accounting).
    const int arow = tid >> 3, ach = tid & 7;
    const int asw = (arow & 3) ^ ((arow >> 2) & 3);
    const float* agp = gA + (size_t)arow * CDIM + ((((ach >> 1) ^ asw) << 3) + (ach & 1) * 4);
    unsigned short* asp0 = &As[0][arow * 32 + (ach << 2)];
    unsigned short* asp1 = &As[1][arow * 32 + (ach << 2)];

    f32x4 acc[6][2];
#pragma unroll
    for (int i = 0; i < 6; i++)
#pragma unroll
        for (int j = 0; j < 2; j++) acc[i][j] = (f32x4)0.f;

    stage_wb(&Bs[0][0], Wt, tid);
    {
        float4 a0 = *(const float4*)(agp);
        ushort4 o;
        o.x = f2bf(a0.x); o.y = f2bf(a0.y); o.z = f2bf(a0.z); o.w = f2bf(a0.w);
        *(ushort4*)asp0 = o;
    }
    __syncthreads();

    int cur = 0;
    for (int kc = 0; kc < CDIM / 32; ++kc){
        float4 a0n;
        if (kc + 1 < CDIM / 32){
            a0n = *(const float4*)(agp + (kc + 1) * 32);          // A first (oldest)
            stage_wb(&Bs[cur ^ 1][0], Wt + (kc + 1) * 32, tid);   // then 3 B loads
            asm volatile("s_waitcnt vmcnt(4)" ::: "memory");
        } else {
            asm volatile("s_waitcnt vmcnt(0)" ::: "memory");
        }
        __builtin_amdgcn_s_barrier();
        __builtin_amdgcn_sched_barrier(0);
        {
            short8 aF[6], bF[2];
#pragma unroll
            for (int i = 0; i < 6; i++){
                int ra = wc * 96 + i * 16 + m;
                int sa = (ra & 3) ^ ((ra >> 2) & 3);
                aF[i] = *(const short8*)&Bs[cur][ra * 32 + ((quad ^ sa) << 3)];
            }
#pragma unroll
            for (int j = 0; j < 2; j++){
                int rn = wr * 32 + j * 16 + m;
                int sb = (rn & 3) ^ ((rn >> 2) & 3);
                bF[j] = *(const short8*)&As[cur][rn * 32 + ((quad ^ sb) << 3)];
            }
#pragma unroll
            for (int i = 0; i < 6; i++)
#pragma unroll
                for (int j = 0; j < 2; j++)
                    acc[i][j] = __builtin_amdgcn_mfma_f32_16x16x32_bf16(aF[i], bF[j], acc[i][j], 0, 0, 0);
        }
        if (kc + 1 < CDIM / 32){
            ushort4 o;
            o.x = f2bf(a0n.x); o.y = f2bf(a0n.y); o.z = f2bf(a0n.z); o.w = f2bf(a0n.w);
            *(ushort4*)((cur == 0) ? asp1 : asp0) = o;
        }
        cur ^= 1;
    }
    __builtin_amdgcn_s_barrier();

    // epilogue: h' = wc*96 + i*16 + quad*4 + r ; t = rb + wr*32 + j*16 + m
    const int b = rb >> 12;
#pragma unroll
    for (int i = 0; i < 6; i++){
        const int hbase = wc * 96 + i * 16;
        const int type = hbase >> 7;              // 0=Q 1=K 2=V (16-row tiles never straddle)
        const int hp = hbase + quad * 4;
#pragma unroll
        for (int j = 0; j < 2; j++){
            const int t = rb + wr * 32 + j * 16 + m;
            if (type == 0){
                ushort4 v;
                v.x = f2bf(acc[i][j][0] * QSCALE); v.y = f2bf(acc[i][j][1] * QSCALE);
                v.z = f2bf(acc[i][j][2] * QSCALE); v.w = f2bf(acc[i][j][3] * QSCALE);
                *(ushort4*)(Qb + (size_t)t * HSD + hp) = v;
            } else if (type == 1){
                ushort4 v;
                v.x = f2bf(acc[i][j][0]); v.y = f2bf(acc[i][j][1]);
                v.z = f2bf(acc[i][j][2]); v.w = f2bf(acc[i][j][3]);
                *(ushort4*)(Kb + (size_t)t * HSD + (hp - 128)) = v;
            } else {
                const int tt = t & (TLEN - 1);
#pragma unroll
                for (int r = 0; r < 4; r++)
                    Vt[((size_t)b * HSD + (hp - 256 + r)) * TLEN + tt] = f2bf(acc[i][j][r]);
            }
        }
    }
}

// ---------------- attention LDS staging (512-thread block, KVBLK=32) ----------------
__device__ __forceinline__ void stage_k_tile(unsigned short* buf, const unsigned short* g,
                                             int tid){
    // 512 slots: 32 rows x 16 chunks of 16B
    int row = tid >> 4;
    int ch  = tid & 15;
    const unsigned short* gp = g + row * 128 + ((ch ^ (row & 15)) << 3);
    unsigned short* lp = buf + (tid << 3);
    __builtin_amdgcn_global_load_lds((const __attribute__((address_space(1))) void*)gp,
                                     (__attribute__((address_space(3))) void*)lp, 16, 0, 0);
}
__device__ __forceinline__ void stage_v_tile(unsigned short* buf, const unsigned short* g,
                                             int tid){
    // 512 slots: 128 rows x 4 chunks of 16B
    int row = tid >> 2;
    int ch  = tid & 3;
    const unsigned short* gp = g + (size_t)row * TLEN + ((ch ^ (row & 3)) << 3);
    unsigned short* lp = buf + (tid << 3);
    __builtin_amdgcn_global_load_lds((const __attribute__((address_space(1))) void*)gp,
                                     (__attribute__((address_space(3))) void*)lp, 16, 0, 0);
}

// ---------------- kernel 3: causal flash attention, static softmax, split-K ----------------
// grid (T/128, nseg, B), block 512 (8 waves x 16 q-rows). KVBLK=32: LDS 32KB total ->
// 4 blocks/CU (2x round-1 residency); finer tiles interleave phases across blocks.
// Counted-vmcnt double buffer: next tile's 2 loads stay in flight across both barriers.
__global__ __launch_bounds__(512, 8) void attn_k(const unsigned short* __restrict__ Qb,
                       const unsigned short* __restrict__ Kb,
                       const unsigned short* __restrict__ Vts,
                       float* __restrict__ Opart, float* __restrict__ lpart, int seglen){
    __shared__ unsigned short Kt[2][32 * 128];   // 2 x 8 KB
    __shared__ unsigned short Vs[2][128 * 32];   // 2 x 8 KB

    const int tid = threadIdx.x, lane = tid & 63, wave = tid >> 6;
    const int m = lane & 15, quad = lane >> 4;
    const int q0 = ((int)gridDim.x - 1 - (int)blockIdx.x) * 128;   // long blocks first
    const int seg = blockIdx.y, b = blockIdx.z;
    const int g0 = seg * seglen;
    if (g0 >= q0 + 128) return;
    const int gend = min(g0 + seglen, q0 + 128);
    const int nT = (gend - g0) >> 5;

    const int q0w = q0 + wave * 16;
    const size_t rowg = (size_t)b * TLEN + q0w;

    const unsigned short* kbase = Kb + (size_t)b * TLEN * HSD;
    const unsigned short* vbase = Vts + (size_t)b * HSD * TLEN;

    // Q fragments (VMEM, resolved in prologue drain)
    short8 aQ[4];
#pragma unroll
    for (int kk = 0; kk < 4; kk++)
        aQ[kk] = *(const short8*)(Qb + (rowg + m) * HSD + kk * 32 + quad * 8);

    // prologue: stage tile 0 into buffer 0 (1 K + 1 V load per thread)
    stage_k_tile(&Kt[0][0], kbase + (size_t)g0 * HSD, tid);
    stage_v_tile(&Vs[0][0], vbase + g0, tid);

    f32x4 accO[8];
#pragma unroll
    for (int i = 0; i < 8; i++) accO[i] = (f32x4)0.f;
    float lp = 0.f;                      // per-lane partial sum for q = m

    // drain ONCE (aQ + tile0), then launder aQ so the compiler's waitcnt pass
    // never re-waits on these loads inside the pipelined loop.
    asm volatile("s_waitcnt vmcnt(0)" ::: "memory");
#pragma unroll
    for (int kk = 0; kk < 4; kk++){
        f32x4 q_ = __builtin_bit_cast(f32x4, aQ[kk]);
        asm volatile("" : "+v"(q_));
        aQ[kk] = __builtin_bit_cast(short8, q_);
    }

    int cur = 0;
    for (int t = 0; t < nT; ++t){
        const int s0 = g0 + t * 32;
        if (t + 1 < nT){                 // prefetch next tile into the other buffer
            stage_k_tile(&Kt[cur ^ 1][0], kbase + (size_t)(s0 + 32) * HSD, tid);
            stage_v_tile(&Vs[cur ^ 1][0], vbase + (s0 + 32), tid);
            // confirm tile t's 2 loads; leave tile t+1's 2 IN FLIGHT across the barriers
            asm volatile("s_waitcnt vmcnt(2)" ::: "memory");
        } else {
            asm volatile("s_waitcnt vmcnt(0)" ::: "memory");
        }
        __builtin_amdgcn_s_barrier();                 // all waves: tile t resident
        __builtin_amdgcn_sched_barrier(0);            // don't hoist ds_reads above barrier
        if (s0 <= q0w + 15){             // wave has at least one live (q,s) pair
            const unsigned short* Ktc = &Kt[cur][0];
            const unsigned short* Vsc = &Vs[cur][0];
            // ---- S^T = K Q^T : rows s=16ns+4quad+r, col q=m
            f32x4 S[2];
            __builtin_amdgcn_s_setprio(1);
#pragma unroll
            for (int ns = 0; ns < 2; ns++){
                f32x4 sa = (f32x4)0.f;
#pragma unroll
                for (int kk = 0; kk < 4; kk++){
                    short8 bK = *(const short8*)&Ktc[(ns * 16 + m) * 128 + (((kk * 4 + quad) ^ m) << 3)];
                    sa = __builtin_amdgcn_mfma_f32_16x16x32_bf16(bK, aQ[kk], sa, 0, 0, 0);
                }
                S[ns] = sa;
            }
            __builtin_amdgcn_s_setprio(0);
            if (s0 + 31 > q0w){          // boundary tile: causal mask s > q
                int qg = q0w + m;
#pragma unroll
                for (int ns = 0; ns < 2; ns++){
#pragma unroll
                    for (int r = 0; r < 4; r++){
                        int sg = s0 + ns * 16 + quad * 4 + r;
                        if (sg > qg) S[ns][r] = -1e30f;   // exp2 -> 0
                    }
                }
            }
            // ---- static softmax: P = exp2(S), lane-local l accumulation
            s4v aP[2];
#pragma unroll
            for (int ns = 0; ns < 2; ns++){
                float p0 = exp2f(S[ns][0]), p1 = exp2f(S[ns][1]);
                float p2 = exp2f(S[ns][2]), p3 = exp2f(S[ns][3]);
                lp += (p0 + p1) + (p2 + p3);
                uint2 u; u.x = pkbf(p0, p1); u.y = pkbf(p2, p3);
                aP[ns] = __builtin_bit_cast(s4v, u);
            }
            // ---- O += P V   (V tile: 128 h-rows x 32 s-cols)
            __builtin_amdgcn_s_setprio(1);
#pragma unroll
            for (int sub = 0; sub < 8; sub++){
#pragma unroll
                for (int ns = 0; ns < 2; ns++){
                    s4v bV = *(const s4v*)&Vsc[(sub * 16 + m) * 32 +
                            (((2 * ns + (quad >> 1)) ^ (m & 3)) << 3) + (quad & 1) * 4];
                    accO[sub] = MFMA16(aP[ns], bV, accO[sub]);
                }
            }
            __builtin_amdgcn_s_setprio(0);
        }
        __builtin_amdgcn_sched_barrier(0);            // don't sink ds_reads below barrier
        __builtin_amdgcn_s_barrier();                 // all waves done reading buf[cur]
        cur ^= 1;
    }
    // ---- epilogue: reduce l across quads (once), write partials
    lp += __shfl_xor(lp, 16, 64);
    lp += __shfl_xor(lp, 32, 64);
    if (quad == 0)
        lpart[(size_t)seg * MROWS + rowg + m] = lp;
    float* ob = Opart + (size_t)seg * MROWS * HSD;
#pragma unroll
    for (int sub = 0; sub < 8; sub++)
#pragma unroll
        for (int r = 0; r < 4; r++)
            ob[(rowg + quad * 4 + r) * HSD + sub * 16 + m] = accO[sub][r];
}

// ---------------- kernel 4: merge split-K partials (plain weighted sum) ----------------
__global__ void merge_k(const float* __restrict__ Opart, const float* __restrict__ lpart,
                        float* __restrict__ out, int nseg, int seglen){
    int idx = blockIdx.x * 256 + threadIdx.x;
    int row = idx >> 7;
    int t = row & (TLEN - 1);
    int q0 = t & ~127;
    int nsv = min(nseg, (q0 + 127) / seglen + 1);
    float L = 0.f, o = 0.f;
    for (int s = 0; s < nsv; s++){
        L += lpart[(size_t)s * MROWS + row];
        o += Opart[(size_t)s * MROWS * HSD + idx];
    }
    out[idx] = o / L;
}

extern "C" void kernel_launch(void* const* d_in, const int* in_sizes, int n_in,
                              void* d_out, int out_size, void* d_ws, size_t ws_size,
                              hipStream_t stream) {
    const float* x  = (const float*)d_in[0];
    const float* Wq = (const float*)d_in[1];
    const float* Wk = (const float*)d_in[2];
    const float* Wv = (const float*)d_in[3];
    float* out = (float*)d_out;
    char* w = (char*)d_ws;

    // layout: Wt@0, Qb@1M, Kb@5M, Vt@9M, lpart@13M (1MB = 16 segs), Opart@14M
    unsigned short* Wt = (unsigned short*)w;
    unsigned short* Qb = (unsigned short*)(w + ((size_t)1u  << 20));
    unsigned short* Kb = (unsigned short*)(w + ((size_t)5u  << 20));
    unsigned short* Vt = (unsigned short*)(w + ((size_t)9u  << 20));
    float* lpart       = (float*)(w + ((size_t)13u << 20));
    float* Opart;
    int nseg;
    const size_t segbytes = (size_t)MROWS * HSD * 4;   // 8.39 MB per segment
    if (ws_size >= ((size_t)14u << 20) + 16 * segbytes){
        nseg = 16; Opart = (float*)(w + ((size_t)14u << 20));
    } else if (ws_size >= ((size_t)14u << 20) + 8 * segbytes){
        nseg = 8;  Opart = (float*)(w + ((size_t)14u << 20));
    } else if (ws_size >= ((size_t)14u << 20) + 4 * segbytes){
        nseg = 4;  Opart = (float*)(w + ((size_t)14u << 20));
    } else {
        nseg = 1;  Opart = out;   // merge then normalizes in place
    }
    const int seglen = TLEN / nseg;

    prep_w_k<<<dim3(CDIM / 32, HSD / 32, 3), 256, 0, stream>>>(Wq, Wk, Wv, Wt);
    proj_k<<<dim3(MROWS / 64), 512, 0, stream>>>(x, Wt, Qb, Kb, Vt);
    attn_k<<<dim3(TLEN / 128, nseg, BATCH), 512, 0, stream>>>(Qb, Kb, Vt, Opart, lpart, seglen);
    merge_k<<<(MROWS * HSD) / 256, 256, 0, stream>>>(Opart, lpart, out, nseg, seglen);
}

// Round 5
// 195.215 us; speedup vs baseline: 1.6058x; 1.6058x over previous
//
#include <hip/hip_runtime.h>
#include <hip/hip_bf16.h>

typedef __attribute__((ext_vector_type(8))) short short8;
typedef __attribute__((ext_vector_type(4))) float f32x4;
typedef __attribute__((ext_vector_type(16))) float f32x16;

#define BATCH 4
#define TLEN 4096
#define CDIM 1024
#define HSD 128
#define MROWS (BATCH*TLEN)

// 1/sqrt(128) * log2(e): fold into Q so softmax runs in exp2 domain
#define QSCALE 0.12751744f

__device__ __forceinline__ unsigned short f2bf(float f){
    unsigned u = __builtin_bit_cast(unsigned, f);
    u = (u + 0x7FFFu + ((u >> 16) & 1u)) >> 16;
    return (unsigned short)u;
}
__device__ __forceinline__ unsigned pkbf(float a, float b){
    unsigned ua = (__builtin_bit_cast(unsigned, a) + 0x8000u) >> 16;
    unsigned ub = (__builtin_bit_cast(unsigned, b) + 0x8000u) & 0xFFFF0000u;
    return ua | ub;
}

// ---------------- kernel 1: W (C,HS) fp32 -> Wt (3,HS,C) bf16, LDS transpose ----------------
__global__ void prep_w_k(const float* __restrict__ Wq, const float* __restrict__ Wk,
                         const float* __restrict__ Wv, unsigned short* __restrict__ Wt){
    __shared__ float tile[32][33];
    const int w = blockIdx.z;
    const float* W = (w == 0) ? Wq : ((w == 1) ? Wk : Wv);
    const int c0 = blockIdx.x * 32, h0 = blockIdx.y * 32;
    const int lx = threadIdx.x & 31, ly = threadIdx.x >> 5;   // ly 0..7
#pragma unroll
    for (int i = 0; i < 4; i++){
        int c = c0 + ly + i * 8;
        tile[ly + i * 8][lx] = W[(size_t)c * HSD + h0 + lx];   // coalesced read over h
    }
    __syncthreads();
#pragma unroll
    for (int i = 0; i < 4; i++){
        int h = h0 + ly + i * 8;
        Wt[((size_t)w * HSD + h) * CDIM + c0 + lx] = f2bf(tile[lx][ly + i * 8]); // coalesced write over c
    }
}

// ---------------- kernel 2: fused QKV projection GEMM (x read ONCE) ----------------
__device__ __forceinline__ void stage_wb(unsigned short* buf, const unsigned short* g, int tid){
#pragma unroll
    for (int i = 0; i < 3; i++){
        int c = i * 512 + tid;              // 1536 chunks: 384 rows x 4 x 16B
        int row = c >> 2, kp = c & 3;
        int swz = (row & 3) ^ ((row >> 2) & 3);
        const unsigned short* gp = g + (size_t)row * CDIM + ((kp ^ swz) << 3);
        unsigned short* lp = buf + (c << 3);
        __builtin_amdgcn_global_load_lds((const __attribute__((address_space(1))) void*)gp,
                                         (__attribute__((address_space(3))) void*)lp, 16, 0, 0);
    }
}

__global__ __launch_bounds__(512) void proj_k(const float* __restrict__ x,
                                              const unsigned short* __restrict__ Wt,
                                              unsigned short* __restrict__ Qb,
                                              unsigned short* __restrict__ Kb,
                                              unsigned short* __restrict__ Vt){
    __shared__ unsigned short As[2][64 * 32];     // 4 KB each
    __shared__ unsigned short Bs[2][384 * 32];    // 24 KB each

    const int tid = threadIdx.x, lane = tid & 63, wave = tid >> 6;
    const int m = lane & 15, quad = lane >> 4;
    const int wr = wave & 1;        // t-half (32 rows)
    const int wc = wave >> 1;       // h-quarter (96 of 384 weight rows)
    const int rb = blockIdx.x * 64;

    const float* gA = x + (size_t)rb * CDIM;

    const int arow = tid >> 3, ach = tid & 7;
    const int asw = (arow & 3) ^ ((arow >> 2) & 3);
    const float* agp = gA + (size_t)arow * CDIM + ((((ach >> 1) ^ asw) << 3) + (ach & 1) * 4);
    unsigned short* asp0 = &As[0][arow * 32 + (ach << 2)];
    unsigned short* asp1 = &As[1][arow * 32 + (ach << 2)];

    f32x4 acc[6][2];
#pragma unroll
    for (int i = 0; i < 6; i++)
#pragma unroll
        for (int j = 0; j < 2; j++) acc[i][j] = (f32x4)0.f;

    stage_wb(&Bs[0][0], Wt, tid);
    {
        float4 a0 = *(const float4*)(agp);
        ushort4 o;
        o.x = f2bf(a0.x); o.y = f2bf(a0.y); o.z = f2bf(a0.z); o.w = f2bf(a0.w);
        *(ushort4*)asp0 = o;
    }
    __syncthreads();

    int cur = 0;
    for (int kc = 0; kc < CDIM / 32; ++kc){
        float4 a0n;
        if (kc + 1 < CDIM / 32){
            a0n = *(const float4*)(agp + (kc + 1) * 32);          // A first (oldest)
            stage_wb(&Bs[cur ^ 1][0], Wt + (kc + 1) * 32, tid);   // then 3 B loads
            asm volatile("s_waitcnt vmcnt(4)" ::: "memory");
        } else {
            asm volatile("s_waitcnt vmcnt(0)" ::: "memory");
        }
        __builtin_amdgcn_s_barrier();
        __builtin_amdgcn_sched_barrier(0);
        {
            short8 aF[6], bF[2];
#pragma unroll
            for (int i = 0; i < 6; i++){
                int ra = wc * 96 + i * 16 + m;
                int sa = (ra & 3) ^ ((ra >> 2) & 3);
                aF[i] = *(const short8*)&Bs[cur][ra * 32 + ((quad ^ sa) << 3)];
            }
#pragma unroll
            for (int j = 0; j < 2; j++){
                int rn = wr * 32 + j * 16 + m;
                int sb = (rn & 3) ^ ((rn >> 2) & 3);
                bF[j] = *(const short8*)&As[cur][rn * 32 + ((quad ^ sb) << 3)];
            }
#pragma unroll
            for (int i = 0; i < 6; i++)
#pragma unroll
                for (int j = 0; j < 2; j++)
                    acc[i][j] = __builtin_amdgcn_mfma_f32_16x16x32_bf16(aF[i], bF[j], acc[i][j], 0, 0, 0);
        }
        if (kc + 1 < CDIM / 32){
            ushort4 o;
            o.x = f2bf(a0n.x); o.y = f2bf(a0n.y); o.z = f2bf(a0n.z); o.w = f2bf(a0n.w);
            *(ushort4*)((cur == 0) ? asp1 : asp0) = o;
        }
        cur ^= 1;
    }
    __builtin_amdgcn_s_barrier();

    const int b = rb >> 12;
#pragma unroll
    for (int i = 0; i < 6; i++){
        const int hbase = wc * 96 + i * 16;
        const int type = hbase >> 7;              // 0=Q 1=K 2=V (16-row tiles never straddle)
        const int hp = hbase + quad * 4;
#pragma unroll
        for (int j = 0; j < 2; j++){
            const int t = rb + wr * 32 + j * 16 + m;
            if (type == 0){
                ushort4 v;
                v.x = f2bf(acc[i][j][0] * QSCALE); v.y = f2bf(acc[i][j][1] * QSCALE);
                v.z = f2bf(acc[i][j][2] * QSCALE); v.w = f2bf(acc[i][j][3] * QSCALE);
                *(ushort4*)(Qb + (size_t)t * HSD + hp) = v;
            } else if (type == 1){
                ushort4 v;
                v.x = f2bf(acc[i][j][0]); v.y = f2bf(acc[i][j][1]);
                v.z = f2bf(acc[i][j][2]); v.w = f2bf(acc[i][j][3]);
                *(ushort4*)(Kb + (size_t)t * HSD + (hp - 128)) = v;
            } else {
                const int tt = t & (TLEN - 1);
#pragma unroll
                for (int r = 0; r < 4; r++)
                    Vt[((size_t)b * HSD + (hp - 256 + r)) * TLEN + tt] = f2bf(acc[i][j][r]);
            }
        }
    }
}

// ---------------- attention LDS staging (256-thread block, KVBLK=32) ----------------
__device__ __forceinline__ void stage_k_tile(unsigned short* buf, const unsigned short* g,
                                             int tid){
#pragma unroll
    for (int i = 0; i < 2; i++){
        int slot = i * 256 + tid;          // 512 slots: 32 rows x 16 chunks of 16B
        int row = slot >> 4;
        int ch  = slot & 15;
        const unsigned short* gp = g + row * 128 + ((ch ^ (row & 15)) << 3);
        unsigned short* lp = buf + (slot << 3);
        __builtin_amdgcn_global_load_lds((const __attribute__((address_space(1))) void*)gp,
                                         (__attribute__((address_space(3))) void*)lp, 16, 0, 0);
    }
}
__device__ __forceinline__ void stage_v_tile(unsigned short* buf, const unsigned short* g,
                                             int tid){
#pragma unroll
    for (int i = 0; i < 2; i++){
        int slot = i * 256 + tid;          // 512 slots: 128 rows x 4 chunks of 16B
        int row = slot >> 2;
        int ch  = slot & 3;
        const unsigned short* gp = g + (size_t)row * TLEN + ((ch ^ (row & 3)) << 3);
        unsigned short* lp = buf + (slot << 3);
        __builtin_amdgcn_global_load_lds((const __attribute__((address_space(1))) void*)gp,
                                         (__attribute__((address_space(3))) void*)lp, 16, 0, 0);
    }
}

// ---------------- kernel 3: causal flash attention, 32x32x16 MFMA ----------------
// grid (T/128, nseg, B), block 256 (4 waves x 32 q-rows). Per 32q x 32s wave-tile:
// QK = 8 mfma_32x32x16 (K in LDS as A, Q in regs as B), softmax in-register,
// P re-fragmented via cvt_pk + v_permlane32_swap (no LDS round-trip), PV = 8 mfma.
// LDS bytes/FLOP halved vs 16x16 version; PV full-rate (K=16 per inst at 32x32).
__global__ __launch_bounds__(256, 3) void attn_k(const unsigned short* __restrict__ Qb,
                       const unsigned short* __restrict__ Kb,
                       const unsigned short* __restrict__ Vts,
                       float* __restrict__ Opart, float* __restrict__ lpart, int seglen){
    __shared__ unsigned short Kt[2][32 * 128];   // 2 x 8 KB
    __shared__ unsigned short Vs[2][128 * 32];   // 2 x 8 KB

    const int tid = threadIdx.x, lane = tid & 63, wave = tid >> 6;   // wave 0..3
    const int col = lane & 31, half = lane >> 5;
    const int q0 = ((int)gridDim.x - 1 - (int)blockIdx.x) * 128;   // long blocks first
    const int seg = blockIdx.y, b = blockIdx.z;
    const int g0 = seg * seglen;
    if (g0 >= q0 + 128) return;
    const int gend = min(g0 + seglen, q0 + 128);
    const int nT = (gend - g0) >> 5;

    const int q0w = q0 + wave * 32;              // wave owns q rows [q0w, q0w+32)
    const size_t rowg = (size_t)b * TLEN + q0w;

    const unsigned short* kbase = Kb + (size_t)b * TLEN * HSD;
    const unsigned short* vbase = Vts + (size_t)b * HSD * TLEN;

    // Q as B-operand fragments: lane holds Q[q0w+col][ks*16 + half*8 + j], j=0..7
    short8 aQ[8];
#pragma unroll
    for (int ks = 0; ks < 8; ks++)
        aQ[ks] = *(const short8*)(Qb + (rowg + col) * HSD + ks * 16 + half * 8);

    // prologue: stage tile 0 into buffer 0 (2 K + 2 V loads per thread)
    stage_k_tile(&Kt[0][0], kbase + (size_t)g0 * HSD, tid);
    stage_v_tile(&Vs[0][0], vbase + g0, tid);

    f32x16 accO[4];
#pragma unroll
    for (int i = 0; i < 4; i++) accO[i] = (f32x16)0.f;
    float lp = 0.f;                      // per-lane partial sum for q = col (half of s-range)

    // drain ONCE (aQ + tile0), then launder aQ so the compiler's waitcnt pass
    // never re-waits on these loads inside the pipelined loop.
    asm volatile("s_waitcnt vmcnt(0)" ::: "memory");
#pragma unroll
    for (int ks = 0; ks < 8; ks++){
        f32x4 q_ = __builtin_bit_cast(f32x4, aQ[ks]);
        asm volatile("" : "+v"(q_));
        aQ[ks] = __builtin_bit_cast(short8, q_);
    }

    int cur = 0;
    for (int t = 0; t < nT; ++t){
        const int s0 = g0 + t * 32;
        if (t + 1 < nT){                 // prefetch next tile into the other buffer
            stage_k_tile(&Kt[cur ^ 1][0], kbase + (size_t)(s0 + 32) * HSD, tid);
            stage_v_tile(&Vs[cur ^ 1][0], vbase + (s0 + 32), tid);
            // confirm tile t's 4 loads; leave tile t+1's 4 IN FLIGHT across the barriers
            asm volatile("s_waitcnt vmcnt(4)" ::: "memory");
        } else {
            asm volatile("s_waitcnt vmcnt(0)" ::: "memory");
        }
        __builtin_amdgcn_s_barrier();                 // all waves: tile t resident
        __builtin_amdgcn_sched_barrier(0);            // don't hoist ds_reads above barrier
        if (s0 <= q0w + 31){             // wave has at least one live (q,s) pair
            const unsigned short* Ktc = &Kt[cur][0];
            const unsigned short* Vsc = &Vs[cur][0];
            // ---- S^T = K Q^T : D[s][q], s = (r&3)+8*(r>>2)+4*half, q = col
            f32x16 S = (f32x16)0.f;
            __builtin_amdgcn_s_setprio(1);
#pragma unroll
            for (int ks = 0; ks < 8; ks++){
                short8 aK = *(const short8*)&Ktc[col * 128 + (((ks * 2 + half) ^ (col & 15)) << 3)];
                S = __builtin_amdgcn_mfma_f32_32x32x16_bf16(aK, aQ[ks], S, 0, 0, 0);
            }
            __builtin_amdgcn_s_setprio(0);
            if (s0 + 31 > q0w){          // boundary tile: causal mask s > q
                int qg = q0w + col;
#pragma unroll
                for (int r = 0; r < 16; r++){
                    int sg = s0 + (r & 3) + 8 * (r >> 2) + 4 * half;
                    if (sg > qg) S[r] = -1e30f;   // exp2 -> 0
                }
            }
            // ---- static softmax: P = exp2(S); lp accumulates this lane's 16 s-values
            float p[16];
#pragma unroll
            for (int r = 0; r < 16; r++) p[r] = exp2f(S[r]);
#pragma unroll
            for (int r = 0; r < 16; r++) lp += p[r];
            // ---- re-fragment P to 32x32x16 A-layout via cvt_pk + permlane32_swap
            // kstep0 (s 0..15): words j01,j23 from own half; j45,j67 from other half
            short8 aP[2];
            {
                unsigned x1 = pkbf(p[0], p[1]), x2 = pkbf(p[2], p[3]);
                unsigned y1 = pkbf(p[4], p[5]), y2 = pkbf(p[6], p[7]);
                asm volatile("v_permlane32_swap_b32 %0, %1" : "+v"(x1), "+v"(y1));
                asm volatile("v_permlane32_swap_b32 %0, %1" : "+v"(x2), "+v"(y2));
                uint4 u; u.x = x1; u.y = x2; u.z = y1; u.w = y2;
                aP[0] = __builtin_bit_cast(short8, u);
                unsigned z1 = pkbf(p[8], p[9]),  z2 = pkbf(p[10], p[11]);
                unsigned w1 = pkbf(p[12], p[13]), w2 = pkbf(p[14], p[15]);
                asm volatile("v_permlane32_swap_b32 %0, %1" : "+v"(z1), "+v"(w1));
                asm volatile("v_permlane32_swap_b32 %0, %1" : "+v"(z2), "+v"(w2));
                uint4 u2; u2.x = z1; u2.y = z2; u2.z = w1; u2.w = w2;
                aP[1] = __builtin_bit_cast(short8, u2);
            }
            // ---- O += P V : B = V[s][h] from LDS, A = aP
            __builtin_amdgcn_s_setprio(1);
#pragma unroll
            for (int ks = 0; ks < 2; ks++){
#pragma unroll
                for (int ht = 0; ht < 4; ht++){
                    short8 bV = *(const short8*)&Vsc[(ht * 32 + col) * 32 +
                            (((ks * 2 + half) ^ (col & 3)) << 3)];
                    accO[ht] = __builtin_amdgcn_mfma_f32_32x32x16_bf16(aP[ks], bV, accO[ht], 0, 0, 0);
                }
            }
            __builtin_amdgcn_s_setprio(0);
        }
        __builtin_amdgcn_sched_barrier(0);            // don't sink ds_reads below barrier
        __builtin_amdgcn_s_barrier();                 // all waves done reading buf[cur]
        cur ^= 1;
    }
    // ---- epilogue: combine the two half-lane partial sums, write partials
    lp += __shfl_xor(lp, 32, 64);
    if (lane < 32)
        lpart[(size_t)seg * MROWS + rowg + col] = lp;
    float* ob = Opart + (size_t)seg * MROWS * HSD;
#pragma unroll
    for (int ht = 0; ht < 4; ht++)
#pragma unroll
        for (int r = 0; r < 16; r++){
            int qrow = (r & 3) + 8 * (r >> 2) + 4 * half;
            ob[(rowg + qrow) * HSD + ht * 32 + col] = accO[ht][r];
        }
}

// ---------------- kernel 4: merge split-K partials (plain weighted sum) ----------------
__global__ void merge_k(const float* __restrict__ Opart, const float* __restrict__ lpart,
                        float* __restrict__ out, int nseg, int seglen){
    int idx = blockIdx.x * 256 + threadIdx.x;
    int row = idx >> 7;
    int t = row & (TLEN - 1);
    int q0 = t & ~127;
    int nsv = min(nseg, (q0 + 127) / seglen + 1);
    float L = 0.f, o = 0.f;
    for (int s = 0; s < nsv; s++){
        L += lpart[(size_t)s * MROWS + row];
        o += Opart[(size_t)s * MROWS * HSD + idx];
    }
    out[idx] = o / L;
}

extern "C" void kernel_launch(void* const* d_in, const int* in_sizes, int n_in,
                              void* d_out, int out_size, void* d_ws, size_t ws_size,
                              hipStream_t stream) {
    const float* x  = (const float*)d_in[0];
    const float* Wq = (const float*)d_in[1];
    const float* Wk = (const float*)d_in[2];
    const float* Wv = (const float*)d_in[3];
    float* out = (float*)d_out;
    char* w = (char*)d_ws;

    // layout: Wt@0, Qb@1M, Kb@5M, Vt@9M, lpart@13M, Opart@14M
    unsigned short* Wt = (unsigned short*)w;
    unsigned short* Qb = (unsigned short*)(w + ((size_t)1u  << 20));
    unsigned short* Kb = (unsigned short*)(w + ((size_t)5u  << 20));
    unsigned short* Vt = (unsigned short*)(w + ((size_t)9u  << 20));
    float* lpart       = (float*)(w + ((size_t)13u << 20));
    float* Opart;
    int nseg;
    const size_t segbytes = (size_t)MROWS * HSD * 4;   // 8.39 MB per segment
    if (ws_size >= ((size_t)14u << 20) + 8 * segbytes){
        nseg = 8;  Opart = (float*)(w + ((size_t)14u << 20));
    } else if (ws_size >= ((size_t)14u << 20) + 4 * segbytes){
        nseg = 4;  Opart = (float*)(w + ((size_t)14u << 20));
    } else {
        nseg = 1;  Opart = out;   // merge then normalizes in place
    }
    const int seglen = TLEN / nseg;

    prep_w_k<<<dim3(CDIM / 32, HSD / 32, 3), 256, 0, stream>>>(Wq, Wk, Wv, Wt);
    proj_k<<<dim3(MROWS / 64), 512, 0, stream>>>(x, Wt, Qb, Kb, Vt);
    attn_k<<<dim3(TLEN / 128, nseg, BATCH), 256, 0, stream>>>(Qb, Kb, Vt, Opart, lpart, seglen);
    merge_k<<<(MROWS * HSD) / 256, 256, 0, stream>>>(Opart, lpart, out, nseg, seglen);
}